// Round 1
// baseline (246.126 us; speedup 1.0000x reference)
//
#include <hip/hip_runtime.h>
#include <cstdint>

#define NN 1024      // nodes
#define NE 16384     // edges
#define DF 256       // features
#define UB 2.0f      // upper bound
#define MAXSEL 6

// ---------------- K1: per-edge L2 distance ----------------
// 4 edges per block (one wave each). f64 accumulation of f32-rounded diffs.
__global__ void k_dist(const float* __restrict__ x, const int* __restrict__ src,
                       const int* __restrict__ dst, float* __restrict__ dist) {
    int e = blockIdx.x * 4 + (threadIdx.x >> 6);
    int lane = threadIdx.x & 63;
    if (e >= NE) return;
    int u = src[e], v = dst[e];
    const float* xu = x + (size_t)u * DF;
    const float* xv = x + (size_t)v * DF;
    double s = 0.0;
    for (int k = lane; k < DF; k += 64) {
        float df = xu[k] - xv[k];          // round diff to f32 like the reference
        double d = (double)df;
        s += d * d;
    }
    for (int off = 32; off; off >>= 1) s += __shfl_xor(s, off, 64);
    if (lane == 0) dist[e] = sqrtf((float)s);
}

// ---------------- K2: min/max + normalize ----------------
__global__ void k_norm(const float* __restrict__ dist, float* __restrict__ score) {
    __shared__ float smn[256], smx[256];
    int t = threadIdx.x;
    float mn = 1e30f, mx = -1e30f;
    for (int e = t; e < NE; e += 256) {
        float d = dist[e];
        mn = fminf(mn, d); mx = fmaxf(mx, d);
    }
    smn[t] = mn; smx[t] = mx; __syncthreads();
    for (int s = 128; s; s >>= 1) {
        if (t < s) { smn[t] = fminf(smn[t], smn[t+s]); smx[t] = fmaxf(smx[t], smx[t+s]); }
        __syncthreads();
    }
    float MN = smn[0], MX = smx[0];
    for (int e = t; e < NE; e += 256)
        score[e] = (dist[e] - MN) / (MX - MN) + 0.5f;
}

// ---------------- CSR build ----------------
__global__ void k_deg(const int* __restrict__ src, int* __restrict__ deg) {
    int e = blockIdx.x * 256 + threadIdx.x;
    if (e < NE) atomicAdd(&deg[src[e]], 1);
}

__global__ void k_scan(const int* __restrict__ deg, int* __restrict__ ptr) {
    __shared__ int buf[NN];
    int t = threadIdx.x;
    int v = deg[t];
    buf[t] = v; __syncthreads();
    for (int off = 1; off < NN; off <<= 1) {
        int add = (t >= off) ? buf[t - off] : 0;
        __syncthreads();
        buf[t] += add;
        __syncthreads();
    }
    ptr[t + 1] = buf[t];
    if (t == 0) ptr[0] = 0;
}

__global__ void k_fill(const int* __restrict__ src, const int* __restrict__ dst,
                       const int* __restrict__ ptr, int* __restrict__ fill,
                       int* __restrict__ cdst, int* __restrict__ ceid) {
    int e = blockIdx.x * 256 + threadIdx.x;
    if (e >= NE) return;
    int u = src[e];
    int pos = ptr[u] + atomicAdd(&fill[u], 1);
    cdst[pos] = dst[e];
    ceid[pos] = e;
}

// ---------------- adjacency bitmask ----------------
__global__ void k_adjbits(const int* __restrict__ src, const int* __restrict__ dst,
                          uint32_t* __restrict__ ADJ) {
    int e = blockIdx.x * 256 + threadIdx.x;
    if (e >= NE) return;
    int u = src[e], v = dst[e];
    atomicOr(&ADJ[(size_t)u * 32 + (v >> 5)], 1u << (v & 31));
}

// ---------------- K3: greedy cluster search (1 wave per seed) ----------------
__global__ void k_search(const int* __restrict__ cptr, const int* __restrict__ cdst,
                         const int* __restrict__ ceid, const float* __restrict__ score,
                         const int* __restrict__ src, const int* __restrict__ dst,
                         uint32_t* __restrict__ masks, int* __restrict__ selU,
                         int* __restrict__ selV, float* __restrict__ selS,
                         int* __restrict__ selCnt) {
    __shared__ uint32_t inc[32];
    __shared__ int members[8];
    __shared__ float s_tot;
    __shared__ int s_nmem;
    int i = blockIdx.x, lane = threadIdx.x;
    if (lane < 32) inc[lane] = 0;
    if (lane == 0) {
        inc[i >> 5] = 1u << (i & 31);
        members[0] = i;
        s_tot = 0.0f;
        s_nmem = 1;
    }
    __syncthreads();
    int cnt = 0;
    for (int step = 0; step < MAXSEL; ++step) {
        if (s_tot >= UB) break;                 // uniform (LDS scalar)
        unsigned long long best = ~0ull;
        int nm = s_nmem;
        for (int m = 0; m < nm; ++m) {
            int u = members[m];
            int b = cptr[u], e2 = cptr[u + 1];
            for (int k = b + lane; k < e2; k += 64) {
                int v = cdst[k];
                if (!((inc[v >> 5] >> (v & 31)) & 1u)) {
                    int e = ceid[k];
                    float s = score[e];
                    unsigned long long key =
                        ((unsigned long long)__float_as_uint(s) << 32) | (unsigned)e;
                    if (key < best) best = key;
                }
            }
        }
        for (int off = 32; off; off >>= 1) {
            unsigned long long o = __shfl_xor(best, off, 64);
            if (o < best) best = o;
        }
        if (best == ~0ull) break;               // no frontier edge
        float s = __uint_as_float((unsigned)(best >> 32));
        int e = (int)(unsigned)best;
        if (lane == 0) {
            int v = dst[e], u = src[e];
            inc[v >> 5] |= 1u << (v & 31);
            members[s_nmem++] = v;
            selU[i * 8 + cnt] = u;
            selV[i * 8 + cnt] = v;
            selS[i * 8 + cnt] = s;
            s_tot += s;                          // f32, same order as reference scan
        }
        cnt++;
        __syncthreads();
    }
    if (lane == 0) selCnt[i] = cnt;
    if (lane < 32) masks[(size_t)i * 32 + lane] = inc[lane];
}

// ---------------- K4: dedup (keep first occurrence of each distinct row) ----
__global__ void k_dedup(const uint32_t* __restrict__ masks, int* __restrict__ keep) {
    __shared__ unsigned long long sig[NN];
    int t = threadIdx.x;
    unsigned long long h = 1469598103934665603ull;
    for (int w = 0; w < 32; ++w) { h ^= masks[(size_t)t * 32 + w]; h *= 1099511628211ull; }
    sig[t] = h; __syncthreads();
    int dup = 0;
    for (int j = 0; j < t; ++j) {
        if (sig[j] == h) {
            bool eq = true;
            for (int w = 0; w < 32; ++w)
                if (masks[(size_t)j * 32 + w] != masks[(size_t)t * 32 + w]) { eq = false; break; }
            if (eq) { dup = 1; break; }
        }
    }
    keep[t] = !dup;
}

// ---------------- K6: adj_new ----------------
__global__ void k_adjnew(const uint32_t* __restrict__ ADJ, const uint32_t* __restrict__ masks,
                         const int* __restrict__ keep, const int* __restrict__ selV,
                         const int* __restrict__ selCnt, float* __restrict__ out) {
    __shared__ uint32_t R[32];
    int i = blockIdx.x, t = threadIdx.x;
    int kp = keep[i];
    if (t < 32) {
        uint32_t r = 0;
        if (kp) {
            r = ADJ[(size_t)i * 32 + t];
            int c = selCnt[i];
            for (int k = 0; k < c; ++k) {
                int v = selV[i * 8 + k];
                r |= ADJ[(size_t)v * 32 + t];
            }
        }
        R[t] = r;
    }
    __syncthreads();
    for (int j = t; j < NN; j += 256) {
        float o = 0.0f;
        if (kp && keep[j] && j != i) {
            const uint32_t* mj = masks + (size_t)j * 32;
            for (int w = 0; w < 32; ++w)
                if (R[w] & mj[w]) { o = 1.0f; break; }
        }
        out[(size_t)i * NN + j] = o;
    }
}

// ---------------- K6b: assign_k and nsm_k rows ----------------
__global__ void k_assign_nsm(const uint32_t* __restrict__ masks, const int* __restrict__ keep,
                             const int* __restrict__ selU, const int* __restrict__ selV,
                             const float* __restrict__ selS, const int* __restrict__ selCnt,
                             float* __restrict__ outA, float* __restrict__ outR) {
    __shared__ int su[8], sv[8];
    __shared__ float ss[8];
    int i = blockIdx.x, t = threadIdx.x;
    int kp = keep[i];
    int c = selCnt[i];
    if (t < 8) { su[t] = selU[i * 8 + t]; sv[t] = selV[i * 8 + t]; ss[t] = selS[i * 8 + t]; }
    __syncthreads();
    for (int n = t; n < NN; n += 256) {
        float a = 0.0f, r = 0.0f;
        if (kp) {
            a = ((masks[(size_t)i * 32 + (n >> 5)] >> (n & 31)) & 1u) ? 1.0f : 0.0f;
            for (int k = 0; k < c; ++k) {
                if (su[k] == n) r += ss[k] * 0.5f;
                if (sv[k] == n) r += ss[k] * 0.5f;
            }
        }
        outA[(size_t)i * NN + n] = a;
        outR[(size_t)i * NN + n] = r;
    }
}

// ---------------- K7: x_new = nsm_k @ x (sparse rows) ----------------
__global__ void k_xnew(const float* __restrict__ x, const int* __restrict__ keep,
                       const int* __restrict__ selU, const int* __restrict__ selV,
                       const float* __restrict__ selS, const int* __restrict__ selCnt,
                       float* __restrict__ out) {
    int i = blockIdx.x, d = threadIdx.x;
    float acc = 0.0f;
    if (keep[i]) {
        int c = selCnt[i];
        for (int k = 0; k < c; ++k) {
            float w = selS[i * 8 + k] * 0.5f;
            acc += w * x[(size_t)selU[i * 8 + k] * DF + d];
            acc += w * x[(size_t)selV[i * 8 + k] * DF + d];
        }
    }
    out[(size_t)i * DF + d] = acc;
}

extern "C" void kernel_launch(void* const* d_in, const int* in_sizes, int n_in,
                              void* d_out, int out_size, void* d_ws, size_t ws_size,
                              hipStream_t stream) {
    const float* x = (const float*)d_in[0];
    const int* ei = (const int*)d_in[1];
    const int* src = ei;
    const int* dst = ei + NE;

    float* out = (float*)d_out;
    float* out_adj = out;                                  // N*N
    float* out_x   = out + (size_t)NN * NN;                // N*D
    float* out_as  = out_x + (size_t)NN * DF;              // N*N
    float* out_nsm = out_as + (size_t)NN * NN;             // N*N

    char* w = (char*)d_ws;
    float*    dist  = (float*)w;     w += (size_t)NE * 4;
    float*    score = (float*)w;     w += (size_t)NE * 4;
    int*      deg   = (int*)w;       w += (size_t)NN * 4;        // zeroed
    int*      fill  = (int*)w;       w += (size_t)NN * 4;        // zeroed
    uint32_t* ADJ   = (uint32_t*)w;  w += (size_t)NN * 32 * 4;   // zeroed
    int*      cptr  = (int*)w;       w += (size_t)(NN + 1) * 4;
    int*      cdst  = (int*)w;       w += (size_t)NE * 4;
    int*      ceid  = (int*)w;       w += (size_t)NE * 4;
    uint32_t* masks = (uint32_t*)w;  w += (size_t)NN * 32 * 4;
    int*      selU  = (int*)w;       w += (size_t)NN * 8 * 4;
    int*      selV  = (int*)w;       w += (size_t)NN * 8 * 4;
    float*    selS  = (float*)w;     w += (size_t)NN * 8 * 4;
    int*      selCnt= (int*)w;       w += (size_t)NN * 4;
    int*      keep  = (int*)w;       w += (size_t)NN * 4;

    // deg, fill, ADJ are contiguous -> single memset
    hipMemsetAsync(deg, 0, ((size_t)NN * 2 + (size_t)NN * 32) * 4, stream);

    k_dist<<<NE / 4, 256, 0, stream>>>(x, src, dst, dist);
    k_norm<<<1, 256, 0, stream>>>(dist, score);
    k_deg<<<NE / 256, 256, 0, stream>>>(src, deg);
    k_scan<<<1, NN, 0, stream>>>(deg, cptr);
    k_fill<<<NE / 256, 256, 0, stream>>>(src, dst, cptr, fill, cdst, ceid);
    k_adjbits<<<NE / 256, 256, 0, stream>>>(src, dst, ADJ);
    k_search<<<NN, 64, 0, stream>>>(cptr, cdst, ceid, score, src, dst,
                                    masks, selU, selV, selS, selCnt);
    k_dedup<<<1, NN, 0, stream>>>(masks, keep);
    k_adjnew<<<NN, 256, 0, stream>>>(ADJ, masks, keep, selV, selCnt, out_adj);
    k_assign_nsm<<<NN, 256, 0, stream>>>(masks, keep, selU, selV, selS, selCnt,
                                         out_as, out_nsm);
    k_xnew<<<NN, 256, 0, stream>>>(x, keep, selU, selV, selS, selCnt, out_x);
}

// Round 2
// 127.041 us; speedup vs baseline: 1.9374x; 1.9374x over previous
//
#include <hip/hip_runtime.h>
#include <cstdint>

#define NN 1024      // nodes
#define NE 16384     // edges
#define DF 256       // features
#define UB 2.0f      // upper bound
#define MAXSEL 6

// ---------------- K1: per-edge L2 distance ----------------
// 4 edges per block (one wave each). f64 accumulation of f32-rounded diffs.
__global__ void k_dist(const float* __restrict__ x, const int* __restrict__ src,
                       const int* __restrict__ dst, float* __restrict__ dist) {
    int e = blockIdx.x * 4 + (threadIdx.x >> 6);
    int lane = threadIdx.x & 63;
    if (e >= NE) return;
    int u = src[e], v = dst[e];
    const float* xu = x + (size_t)u * DF;
    const float* xv = x + (size_t)v * DF;
    double s = 0.0;
    for (int k = lane; k < DF; k += 64) {
        float df = xu[k] - xv[k];          // round diff to f32 like the reference
        double d = (double)df;
        s += d * d;
    }
    for (int off = 32; off; off >>= 1) s += __shfl_xor(s, off, 64);
    if (lane == 0) dist[e] = sqrtf((float)s);
}

// ---------------- K2: min/max + normalize ----------------
__global__ void k_norm(const float* __restrict__ dist, float* __restrict__ score) {
    __shared__ float smn[256], smx[256];
    int t = threadIdx.x;
    float mn = 1e30f, mx = -1e30f;
    for (int e = t; e < NE; e += 256) {
        float d = dist[e];
        mn = fminf(mn, d); mx = fmaxf(mx, d);
    }
    smn[t] = mn; smx[t] = mx; __syncthreads();
    for (int s = 128; s; s >>= 1) {
        if (t < s) { smn[t] = fminf(smn[t], smn[t+s]); smx[t] = fmaxf(smx[t], smx[t+s]); }
        __syncthreads();
    }
    float MN = smn[0], MX = smx[0];
    for (int e = t; e < NE; e += 256)
        score[e] = (dist[e] - MN) / (MX - MN) + 0.5f;
}

// ---------------- per-edge: degree count + adjacency bitmask (merged) -------
__global__ void k_deg_adj(const int* __restrict__ src, const int* __restrict__ dst,
                          int* __restrict__ deg, uint32_t* __restrict__ ADJ) {
    int e = blockIdx.x * 256 + threadIdx.x;
    if (e >= NE) return;
    int u = src[e], v = dst[e];
    atomicAdd(&deg[u], 1);
    atomicOr(&ADJ[(size_t)u * 32 + (v >> 5)], 1u << (v & 31));
}

__global__ void k_scan(const int* __restrict__ deg, int* __restrict__ ptr) {
    __shared__ int buf[NN];
    int t = threadIdx.x;
    int v = deg[t];
    buf[t] = v; __syncthreads();
    for (int off = 1; off < NN; off <<= 1) {
        int add = (t >= off) ? buf[t - off] : 0;
        __syncthreads();
        buf[t] += add;
        __syncthreads();
    }
    ptr[t + 1] = buf[t];
    if (t == 0) ptr[0] = 0;
}

__global__ void k_fill(const int* __restrict__ src, const int* __restrict__ dst,
                       const int* __restrict__ ptr, int* __restrict__ fill,
                       int* __restrict__ cdst, int* __restrict__ ceid) {
    int e = blockIdx.x * 256 + threadIdx.x;
    if (e >= NE) return;
    int u = src[e];
    int pos = ptr[u] + atomicAdd(&fill[u], 1);
    cdst[pos] = dst[e];
    ceid[pos] = e;
}

// ---------------- K3: greedy cluster search (1 wave per seed) ----------------
__global__ void k_search(const int* __restrict__ cptr, const int* __restrict__ cdst,
                         const int* __restrict__ ceid, const float* __restrict__ score,
                         const int* __restrict__ src, const int* __restrict__ dst,
                         uint32_t* __restrict__ masks, int* __restrict__ selU,
                         int* __restrict__ selV, float* __restrict__ selS,
                         int* __restrict__ selCnt, unsigned long long* __restrict__ sig) {
    __shared__ uint32_t inc[32];
    __shared__ int members[8];
    __shared__ float s_tot;
    __shared__ int s_nmem;
    int i = blockIdx.x, lane = threadIdx.x;
    if (lane < 32) inc[lane] = 0;
    if (lane == 0) {
        inc[i >> 5] = 1u << (i & 31);
        members[0] = i;
        s_tot = 0.0f;
        s_nmem = 1;
    }
    __syncthreads();
    int cnt = 0;
    for (int step = 0; step < MAXSEL; ++step) {
        if (s_tot >= UB) break;                 // uniform (LDS scalar)
        unsigned long long best = ~0ull;
        int nm = s_nmem;
        for (int m = 0; m < nm; ++m) {
            int u = members[m];
            int b = cptr[u], e2 = cptr[u + 1];
            for (int k = b + lane; k < e2; k += 64) {
                int v = cdst[k];
                if (!((inc[v >> 5] >> (v & 31)) & 1u)) {
                    int e = ceid[k];
                    float s = score[e];
                    unsigned long long key =
                        ((unsigned long long)__float_as_uint(s) << 32) | (unsigned)e;
                    if (key < best) best = key;
                }
            }
        }
        for (int off = 32; off; off >>= 1) {
            unsigned long long o = __shfl_xor(best, off, 64);
            if (o < best) best = o;
        }
        if (best == ~0ull) break;               // no frontier edge
        float s = __uint_as_float((unsigned)(best >> 32));
        int e = (int)(unsigned)best;
        if (lane == 0) {
            int v = dst[e], u = src[e];
            inc[v >> 5] |= 1u << (v & 31);
            members[s_nmem++] = v;
            selU[i * 8 + cnt] = u;
            selV[i * 8 + cnt] = v;
            selS[i * 8 + cnt] = s;
            s_tot += s;                          // f32, same order as reference scan
        }
        cnt++;
        __syncthreads();
    }
    if (lane == 0) {
        selCnt[i] = cnt;
        unsigned long long h = 1469598103934665603ull;
        for (int w = 0; w < 32; ++w) { h ^= inc[w]; h *= 1099511628211ull; }
        sig[i] = h;
    }
    if (lane < 32) masks[(size_t)i * 32 + lane] = inc[lane];
}

// ---------------- K4: dedup, parallel (block i checks all j < i) ------------
__global__ void k_dedup(const uint32_t* __restrict__ masks,
                        const unsigned long long* __restrict__ sig,
                        int* __restrict__ keep) {
    __shared__ int s_dup;
    int i = blockIdx.x, t = threadIdx.x;
    if (t == 0) s_dup = 0;
    __syncthreads();
    unsigned long long h = sig[i];
    int dup = 0;
    for (int j = t; j < i; j += 256) {
        if (sig[j] == h) {
            const uint32_t* mi = masks + (size_t)i * 32;
            const uint32_t* mj = masks + (size_t)j * 32;
            bool eq = true;
            for (int w = 0; w < 32 && eq; ++w) eq = (mi[w] == mj[w]);
            if (eq) dup = 1;
        }
    }
    if (__any(dup)) { if ((t & 63) == 0) s_dup = 1; }
    __syncthreads();
    if (t == 0) keep[i] = !s_dup;
}

// ---------------- K6: adj_new ----------------
__global__ void k_adjnew(const uint32_t* __restrict__ ADJ, const uint32_t* __restrict__ masks,
                         const int* __restrict__ keep, const int* __restrict__ selV,
                         const int* __restrict__ selCnt, float* __restrict__ out) {
    __shared__ uint32_t R[32];
    int i = blockIdx.x, t = threadIdx.x;
    int kp = keep[i];
    if (t < 32) {
        uint32_t r = 0;
        if (kp) {
            r = ADJ[(size_t)i * 32 + t];
            int c = selCnt[i];
            for (int k = 0; k < c; ++k) {
                int v = selV[i * 8 + k];
                r |= ADJ[(size_t)v * 32 + t];
            }
        }
        R[t] = r;
    }
    __syncthreads();
    for (int j = t; j < NN; j += 256) {
        float o = 0.0f;
        if (kp && keep[j] && j != i) {
            const uint32_t* mj = masks + (size_t)j * 32;
            for (int w = 0; w < 32; ++w)
                if (R[w] & mj[w]) { o = 1.0f; break; }
        }
        out[(size_t)i * NN + j] = o;
    }
}

// ---------------- K6b: assign_k and nsm_k rows ----------------
__global__ void k_assign_nsm(const uint32_t* __restrict__ masks, const int* __restrict__ keep,
                             const int* __restrict__ selU, const int* __restrict__ selV,
                             const float* __restrict__ selS, const int* __restrict__ selCnt,
                             float* __restrict__ outA, float* __restrict__ outR) {
    __shared__ int su[8], sv[8];
    __shared__ float ss[8];
    int i = blockIdx.x, t = threadIdx.x;
    int kp = keep[i];
    int c = selCnt[i];
    if (t < 8) { su[t] = selU[i * 8 + t]; sv[t] = selV[i * 8 + t]; ss[t] = selS[i * 8 + t]; }
    __syncthreads();
    for (int n = t; n < NN; n += 256) {
        float a = 0.0f, r = 0.0f;
        if (kp) {
            a = ((masks[(size_t)i * 32 + (n >> 5)] >> (n & 31)) & 1u) ? 1.0f : 0.0f;
            for (int k = 0; k < c; ++k) {
                if (su[k] == n) r += ss[k] * 0.5f;
                if (sv[k] == n) r += ss[k] * 0.5f;
            }
        }
        outA[(size_t)i * NN + n] = a;
        outR[(size_t)i * NN + n] = r;
    }
}

// ---------------- K7: x_new = nsm_k @ x (sparse rows) ----------------
__global__ void k_xnew(const float* __restrict__ x, const int* __restrict__ keep,
                       const int* __restrict__ selU, const int* __restrict__ selV,
                       const float* __restrict__ selS, const int* __restrict__ selCnt,
                       float* __restrict__ out) {
    int i = blockIdx.x, d = threadIdx.x;
    float acc = 0.0f;
    if (keep[i]) {
        int c = selCnt[i];
        for (int k = 0; k < c; ++k) {
            float w = selS[i * 8 + k] * 0.5f;
            acc += w * x[(size_t)selU[i * 8 + k] * DF + d];
            acc += w * x[(size_t)selV[i * 8 + k] * DF + d];
        }
    }
    out[(size_t)i * DF + d] = acc;
}

extern "C" void kernel_launch(void* const* d_in, const int* in_sizes, int n_in,
                              void* d_out, int out_size, void* d_ws, size_t ws_size,
                              hipStream_t stream) {
    const float* x = (const float*)d_in[0];
    const int* ei = (const int*)d_in[1];
    const int* src = ei;
    const int* dst = ei + NE;

    float* out = (float*)d_out;
    float* out_adj = out;                                  // N*N
    float* out_x   = out + (size_t)NN * NN;                // N*D
    float* out_as  = out_x + (size_t)NN * DF;              // N*N
    float* out_nsm = out_as + (size_t)NN * NN;             // N*N

    char* w = (char*)d_ws;
    unsigned long long* sig = (unsigned long long*)w; w += (size_t)NN * 8;  // 8B-aligned (first)
    float*    dist  = (float*)w;     w += (size_t)NE * 4;
    float*    score = (float*)w;     w += (size_t)NE * 4;
    int*      deg   = (int*)w;       w += (size_t)NN * 4;        // zeroed
    int*      fill  = (int*)w;       w += (size_t)NN * 4;        // zeroed
    uint32_t* ADJ   = (uint32_t*)w;  w += (size_t)NN * 32 * 4;   // zeroed
    int*      cptr  = (int*)w;       w += (size_t)(NN + 1) * 4;
    int*      cdst  = (int*)w;       w += (size_t)NE * 4;
    int*      ceid  = (int*)w;       w += (size_t)NE * 4;
    uint32_t* masks = (uint32_t*)w;  w += (size_t)NN * 32 * 4;
    int*      selU  = (int*)w;       w += (size_t)NN * 8 * 4;
    int*      selV  = (int*)w;       w += (size_t)NN * 8 * 4;
    float*    selS  = (float*)w;     w += (size_t)NN * 8 * 4;
    int*      selCnt= (int*)w;       w += (size_t)NN * 4;
    int*      keep  = (int*)w;       w += (size_t)NN * 4;

    // deg, fill, ADJ are contiguous -> single memset
    hipMemsetAsync(deg, 0, ((size_t)NN * 2 + (size_t)NN * 32) * 4, stream);

    k_dist<<<NE / 4, 256, 0, stream>>>(x, src, dst, dist);
    k_norm<<<1, 256, 0, stream>>>(dist, score);
    k_deg_adj<<<NE / 256, 256, 0, stream>>>(src, dst, deg, ADJ);
    k_scan<<<1, NN, 0, stream>>>(deg, cptr);
    k_fill<<<NE / 256, 256, 0, stream>>>(src, dst, cptr, fill, cdst, ceid);
    k_search<<<NN, 64, 0, stream>>>(cptr, cdst, ceid, score, src, dst,
                                    masks, selU, selV, selS, selCnt, sig);
    k_dedup<<<NN, 256, 0, stream>>>(masks, sig, keep);
    k_adjnew<<<NN, 256, 0, stream>>>(ADJ, masks, keep, selV, selCnt, out_adj);
    k_assign_nsm<<<NN, 256, 0, stream>>>(masks, keep, selU, selV, selS, selCnt,
                                         out_as, out_nsm);
    k_xnew<<<NN, 256, 0, stream>>>(x, keep, selU, selV, selS, selCnt, out_x);
}

// Round 3
// 73.456 us; speedup vs baseline: 3.3506x; 1.7295x over previous
//
#include <hip/hip_runtime.h>
#include <cstdint>

#define NN 1024      // nodes
#define NE 16384     // edges
#define DF 256       // features
#define UB 2.0f      // upper bound
#define MAXSEL 6

// ---------------- K1: per-edge L2 distance ----------------
__global__ void k_dist(const float* __restrict__ x, const int* __restrict__ src,
                       const int* __restrict__ dst, float* __restrict__ dist) {
    int e = blockIdx.x * 4 + (threadIdx.x >> 6);
    int lane = threadIdx.x & 63;
    if (e >= NE) return;
    int u = src[e], v = dst[e];
    const float* xu = x + (size_t)u * DF;
    const float* xv = x + (size_t)v * DF;
    double s = 0.0;
    for (int k = lane; k < DF; k += 64) {
        float df = xu[k] - xv[k];          // round diff to f32 like the reference
        double d = (double)df;
        s += d * d;
    }
    for (int off = 32; off; off >>= 1) s += __shfl_xor(s, off, 64);
    if (lane == 0) dist[e] = sqrtf((float)s);
}

// ---------------- K2: min/max + normalize ----------------
__global__ void k_norm(const float* __restrict__ dist, float* __restrict__ score) {
    __shared__ float smn[256], smx[256];
    int t = threadIdx.x;
    float mn = 1e30f, mx = -1e30f;
    for (int e = t; e < NE; e += 256) {
        float d = dist[e];
        mn = fminf(mn, d); mx = fmaxf(mx, d);
    }
    smn[t] = mn; smx[t] = mx; __syncthreads();
    for (int s = 128; s; s >>= 1) {
        if (t < s) { smn[t] = fminf(smn[t], smn[t+s]); smx[t] = fmaxf(smx[t], smx[t+s]); }
        __syncthreads();
    }
    float MN = smn[0], MX = smx[0];
    for (int e = t; e < NE; e += 256)
        score[e] = (dist[e] - MN) / (MX - MN) + 0.5f;
}

// ---------------- per-edge: degree count + adjacency bitmask ----------------
__global__ void k_deg_adj(const int* __restrict__ src, const int* __restrict__ dst,
                          int* __restrict__ deg, uint32_t* __restrict__ ADJ) {
    int e = blockIdx.x * 256 + threadIdx.x;
    if (e >= NE) return;
    int u = src[e], v = dst[e];
    atomicAdd(&deg[u], 1);
    atomicOr(&ADJ[(size_t)u * 32 + (v >> 5)], 1u << (v & 31));
}

__global__ void k_scan(const int* __restrict__ deg, int* __restrict__ ptr) {
    __shared__ int buf[NN];
    int t = threadIdx.x;
    int v = deg[t];
    buf[t] = v; __syncthreads();
    for (int off = 1; off < NN; off <<= 1) {
        int add = (t >= off) ? buf[t - off] : 0;
        __syncthreads();
        buf[t] += add;
        __syncthreads();
    }
    ptr[t + 1] = buf[t];
    if (t == 0) ptr[0] = 0;
}

__global__ void k_fill(const int* __restrict__ src, const int* __restrict__ dst,
                       const int* __restrict__ ptr, int* __restrict__ fill,
                       int* __restrict__ cdst, int* __restrict__ ceid) {
    int e = blockIdx.x * 256 + threadIdx.x;
    if (e >= NE) return;
    int u = src[e];
    int pos = ptr[u] + atomicAdd(&fill[u], 1);
    cdst[pos] = dst[e];
    ceid[pos] = e;
}

// ---------------- K3: greedy cluster search (1 wave per seed) ----------------
__global__ void k_search(const int* __restrict__ cptr, const int* __restrict__ cdst,
                         const int* __restrict__ ceid, const float* __restrict__ score,
                         const int* __restrict__ src, const int* __restrict__ dst,
                         uint32_t* __restrict__ masks, int* __restrict__ selU,
                         int* __restrict__ selV, float* __restrict__ selS,
                         int* __restrict__ selCnt, unsigned long long* __restrict__ sig) {
    __shared__ uint32_t inc[32];
    __shared__ int members[8];
    __shared__ float s_tot;
    __shared__ int s_nmem;
    int i = blockIdx.x, lane = threadIdx.x;
    if (lane < 32) inc[lane] = 0;
    if (lane == 0) {
        inc[i >> 5] = 1u << (i & 31);
        members[0] = i;
        s_tot = 0.0f;
        s_nmem = 1;
    }
    __syncthreads();
    int cnt = 0;
    for (int step = 0; step < MAXSEL; ++step) {
        if (s_tot >= UB) break;                 // uniform (LDS scalar)
        unsigned long long best = ~0ull;
        int nm = s_nmem;
        for (int m = 0; m < nm; ++m) {
            int u = members[m];
            int b = cptr[u], e2 = cptr[u + 1];
            for (int k = b + lane; k < e2; k += 64) {
                int v = cdst[k];
                if (!((inc[v >> 5] >> (v & 31)) & 1u)) {
                    int e = ceid[k];
                    float s = score[e];
                    unsigned long long key =
                        ((unsigned long long)__float_as_uint(s) << 32) | (unsigned)e;
                    if (key < best) best = key;
                }
            }
        }
        for (int off = 32; off; off >>= 1) {
            unsigned long long o = __shfl_xor(best, off, 64);
            if (o < best) best = o;
        }
        if (best == ~0ull) break;               // no frontier edge
        float s = __uint_as_float((unsigned)(best >> 32));
        int e = (int)(unsigned)best;
        if (lane == 0) {
            int v = dst[e], u = src[e];
            inc[v >> 5] |= 1u << (v & 31);
            members[s_nmem++] = v;
            selU[i * 8 + cnt] = u;
            selV[i * 8 + cnt] = v;
            selS[i * 8 + cnt] = s;
            s_tot += s;                          // f32, same order as reference scan
        }
        cnt++;
        __syncthreads();
    }
    if (lane == 0) {
        selCnt[i] = cnt;
        unsigned long long h = 1469598103934665603ull;
        for (int w = 0; w < 32; ++w) { h ^= inc[w]; h *= 1099511628211ull; }
        sig[i] = h;
    }
    if (lane < 32) masks[(size_t)i * 32 + lane] = inc[lane];
}

// ------- K4: dedup (parallel) + scatter kept-cluster bits into maskT --------
// maskT[n] = 1024-bit vector over clusters j: bit j set iff keep[j] && n ∈ cluster j
__global__ void k_dedup(const uint32_t* __restrict__ masks,
                        const unsigned long long* __restrict__ sig,
                        const int* __restrict__ selV, const int* __restrict__ selCnt,
                        int* __restrict__ keep, uint32_t* __restrict__ maskT) {
    __shared__ int s_dup;
    int i = blockIdx.x, t = threadIdx.x;
    if (t == 0) s_dup = 0;
    __syncthreads();
    unsigned long long h = sig[i];
    int dup = 0;
    for (int j = t; j < i; j += 256) {
        if (sig[j] == h) {
            const uint32_t* mi = masks + (size_t)i * 32;
            const uint32_t* mj = masks + (size_t)j * 32;
            bool eq = true;
            for (int w = 0; w < 32 && eq; ++w) eq = (mi[w] == mj[w]);
            if (eq) dup = 1;
        }
    }
    if (__any(dup)) { if ((t & 63) == 0) s_dup = 1; }
    __syncthreads();
    int kp = !s_dup;
    if (t == 0) keep[i] = kp;
    if (kp) {
        int wrd = i >> 5;
        uint32_t bit = 1u << (i & 31);
        if (t == 0) atomicOr(&maskT[(size_t)i * 32 + wrd], bit);      // self
        int c = selCnt[i];
        if (t >= 1 && t <= c) {
            int v = selV[i * 8 + (t - 1)];
            atomicOr(&maskT[(size_t)v * 32 + wrd], bit);
        }
    }
}

// ------- K5: all four outputs, one block per row i --------------------------
__global__ void k_rows(const float* __restrict__ x, const uint32_t* __restrict__ ADJ,
                       const uint32_t* __restrict__ masks, const uint32_t* __restrict__ maskT,
                       const int* __restrict__ keep, const int* __restrict__ selU,
                       const int* __restrict__ selV, const float* __restrict__ selS,
                       const int* __restrict__ selCnt,
                       float* __restrict__ outAdj, float* __restrict__ outAs,
                       float* __restrict__ outNsm, float* __restrict__ outX) {
    __shared__ uint32_t R[32];        // nodes reachable by 1 edge from cluster i
    __shared__ uint32_t MI[32];       // cluster-i membership bits
    __shared__ uint32_t part[8][32];
    __shared__ uint32_t orow[32];     // adj_new row i as bits over j
    __shared__ int su[8], sv[8];
    __shared__ float ss[8];
    __shared__ int s_c;
    int i = blockIdx.x, t = threadIdx.x;
    int kp = keep[i];
    if (t == 0) s_c = selCnt[i];
    if (t < 8) { su[t] = selU[i*8+t]; sv[t] = selV[i*8+t]; ss[t] = selS[i*8+t]; }
    __syncthreads();
    int c = s_c;
    if (t < 32) {
        uint32_t r = ADJ[(size_t)i * 32 + t];
        for (int k = 0; k < c; ++k) r |= ADJ[(size_t)sv[k] * 32 + t];
        R[t] = r;
        MI[t] = masks[(size_t)i * 32 + t];
    }
    __syncthreads();
    // orow = OR over set bits n of R of maskT[n]   (8 groups x 32 lanes)
    int g = t >> 5, l = t & 31;
    uint32_t acc = 0;
    if (kp) {
        for (int wi = g; wi < 32; wi += 8) {
            uint32_t bits = R[wi];
            while (bits) {
                int b = __ffs(bits) - 1;
                bits &= bits - 1;
                acc |= maskT[((size_t)(wi * 32 + b)) * 32 + l];   // coalesced over l
            }
        }
    }
    part[g][l] = acc;
    __syncthreads();
    if (t < 32) {
        uint32_t o = 0;
        for (int gg = 0; gg < 8; ++gg) o |= part[gg][t];
        orow[t] = o;
    }
    __syncthreads();

    // ---- writes: thread t owns j0 = 4t .. 4t+3 (float4, fully coalesced) ----
    int j0 = t * 4;
    int w = j0 >> 5, sh = j0 & 31;
    float4 vadj = {0,0,0,0}, vas = {0,0,0,0}, vnsm = {0,0,0,0};
    if (kp) {
        uint32_t ob = orow[w] >> sh;
        uint32_t mb = MI[w] >> sh;
        vadj.x = ((ob     ) & 1) && (j0     != i) ? 1.0f : 0.0f;
        vadj.y = ((ob >> 1) & 1) && (j0 + 1 != i) ? 1.0f : 0.0f;
        vadj.z = ((ob >> 2) & 1) && (j0 + 2 != i) ? 1.0f : 0.0f;
        vadj.w = ((ob >> 3) & 1) && (j0 + 3 != i) ? 1.0f : 0.0f;
        vas.x = (mb      & 1) ? 1.0f : 0.0f;
        vas.y = ((mb>>1) & 1) ? 1.0f : 0.0f;
        vas.z = ((mb>>2) & 1) ? 1.0f : 0.0f;
        vas.w = ((mb>>3) & 1) ? 1.0f : 0.0f;
        for (int k = 0; k < c; ++k) {
            float h = ss[k] * 0.5f;
            int u = su[k], v = sv[k];
            vnsm.x += ((u == j0    ) ? h : 0.0f) + ((v == j0    ) ? h : 0.0f);
            vnsm.y += ((u == j0 + 1) ? h : 0.0f) + ((v == j0 + 1) ? h : 0.0f);
            vnsm.z += ((u == j0 + 2) ? h : 0.0f) + ((v == j0 + 2) ? h : 0.0f);
            vnsm.w += ((u == j0 + 3) ? h : 0.0f) + ((v == j0 + 3) ? h : 0.0f);
        }
    }
    ((float4*)outAdj)[(size_t)i * (NN/4) + t] = vadj;
    ((float4*)outAs )[(size_t)i * (NN/4) + t] = vas;
    ((float4*)outNsm)[(size_t)i * (NN/4) + t] = vnsm;

    // ---- x_new row i: thread t = feature dim ----
    float accx = 0.0f;
    if (kp) {
        for (int k = 0; k < c; ++k) {
            float h = ss[k] * 0.5f;
            accx += h * x[(size_t)su[k] * DF + t];
            accx += h * x[(size_t)sv[k] * DF + t];
        }
    }
    outX[(size_t)i * DF + t] = accx;
}

extern "C" void kernel_launch(void* const* d_in, const int* in_sizes, int n_in,
                              void* d_out, int out_size, void* d_ws, size_t ws_size,
                              hipStream_t stream) {
    const float* x = (const float*)d_in[0];
    const int* ei = (const int*)d_in[1];
    const int* src = ei;
    const int* dst = ei + NE;

    float* out = (float*)d_out;
    float* out_adj = out;                                  // N*N
    float* out_x   = out + (size_t)NN * NN;                // N*D
    float* out_as  = out_x + (size_t)NN * DF;              // N*N
    float* out_nsm = out_as + (size_t)NN * NN;             // N*N

    char* w = (char*)d_ws;
    unsigned long long* sig = (unsigned long long*)w; w += (size_t)NN * 8;
    float*    dist  = (float*)w;     w += (size_t)NE * 4;
    float*    score = (float*)w;     w += (size_t)NE * 4;
    // ---- zeroed region (contiguous): deg, fill, ADJ, maskT ----
    int*      deg   = (int*)w;       w += (size_t)NN * 4;
    int*      fill  = (int*)w;       w += (size_t)NN * 4;
    uint32_t* ADJ   = (uint32_t*)w;  w += (size_t)NN * 32 * 4;
    uint32_t* maskT = (uint32_t*)w;  w += (size_t)NN * 32 * 4;
    // ---- end zeroed region ----
    int*      cptr  = (int*)w;       w += (size_t)(NN + 1) * 4;
    int*      cdst  = (int*)w;       w += (size_t)NE * 4;
    int*      ceid  = (int*)w;       w += (size_t)NE * 4;
    uint32_t* masks = (uint32_t*)w;  w += (size_t)NN * 32 * 4;
    int*      selU  = (int*)w;       w += (size_t)NN * 8 * 4;
    int*      selV  = (int*)w;       w += (size_t)NN * 8 * 4;
    float*    selS  = (float*)w;     w += (size_t)NN * 8 * 4;
    int*      selCnt= (int*)w;       w += (size_t)NN * 4;
    int*      keep  = (int*)w;       w += (size_t)NN * 4;

    hipMemsetAsync(deg, 0, ((size_t)NN * 2 + (size_t)NN * 64) * 4, stream);

    k_dist<<<NE / 4, 256, 0, stream>>>(x, src, dst, dist);
    k_norm<<<1, 256, 0, stream>>>(dist, score);
    k_deg_adj<<<NE / 256, 256, 0, stream>>>(src, dst, deg, ADJ);
    k_scan<<<1, NN, 0, stream>>>(deg, cptr);
    k_fill<<<NE / 256, 256, 0, stream>>>(src, dst, cptr, fill, cdst, ceid);
    k_search<<<NN, 64, 0, stream>>>(cptr, cdst, ceid, score, src, dst,
                                    masks, selU, selV, selS, selCnt, sig);
    k_dedup<<<NN, 256, 0, stream>>>(masks, sig, selV, selCnt, keep, maskT);
    k_rows<<<NN, 256, 0, stream>>>(x, ADJ, masks, maskT, keep, selU, selV, selS, selCnt,
                                   out_adj, out_as, out_nsm, out_x);
}